// Round 7
// baseline (1184.139 us; speedup 1.0000x reference)
//
#include <hip/hip_runtime.h>
#include <hip/hip_bf16.h>

// Problem constants (WholeBrainRateModel)
constexpr int kN   = 50000;    // nodes
constexpr int kH   = 64;       // hidden
constexpr int kB   = 2;        // batch
constexpr int kE   = 1000000;  // edges
constexpr int kObs = 128;
constexpr int kA   = 18;
constexpr int kAff = 512;
constexpr int kEff = 256;
constexpr int kNH  = kN * kH;
constexpr int kOutOff = 2 * kB * kA;  // 72 elements: mean+log_std before next_state
constexpr int kHistBlocks = (kE + 1023) / 1024;  // 977 (4 edges/thread, 256 thr)
constexpr int kNB  = 782;        // node buckets (64 nodes each), 782*64 >= 50000
constexpr int kVB  = kNB * 8;    // 6256 virtual buckets (8 XCD-keyed replicas)

typedef __attribute__((ext_vector_type(8))) short short8_t;  // 8 bf16 (4 VGPRs)
typedef __attribute__((ext_vector_type(4))) float f32x4_t;

// dtype-adaptive load/store (flag==1 -> float32 buffers, else bf16).
__device__ __forceinline__ float ldf(const void* p, int i, int f32) {
  if (f32) return ((const float*)p)[i];
  unsigned short u = ((const unsigned short*)p)[i];
  union { unsigned int x; float f; } v; v.x = ((unsigned int)u) << 16; return v.f;
}
__device__ __forceinline__ void stf(void* p, int i, float val, int f32) {
  if (f32) ((float*)p)[i] = val;
  else ((__hip_bfloat16*)p)[i] = __float2bfloat16(val);
}
__device__ __forceinline__ float lo16(unsigned int w) {
  union { unsigned int i; float f; } v; v.i = w << 16; return v.f;
}
__device__ __forceinline__ float hi16(unsigned int w) {
  union { unsigned int i; float f; } v; v.i = w & 0xffff0000u; return v.f;
}
__device__ __forceinline__ unsigned int f2b(float f) {  // rne bf16 bits
  union { float f; unsigned int u; } v; v.f = f;
  unsigned int r = v.u + 0x7fffu + ((v.u >> 16) & 1u);
  return r >> 16;
}

// --- fused: block0 = detect + flags + obs@W_in; rest = virtual-bucket hist --
// rep key (e>>10)&7 == (edge-block index)&7: stable per block, XCD-aligned
// under round-robin dispatch, and identically computable in k_bscatter.
extern "C" __global__ void k_front(const unsigned short* __restrict__ wprobe,
                                   const void* __restrict__ obs,
                                   const void* __restrict__ W_in,
                                   const void* __restrict__ b_in,
                                   const int* __restrict__ aff_idx,
                                   const int* __restrict__ dst,
                                   int* __restrict__ dflag,
                                   int* __restrict__ flags,
                                   float* __restrict__ projected,
                                   int* __restrict__ vbh) {
  int t = threadIdx.x;
  if (blockIdx.x == 0) {
    __shared__ int sflag;
    if (t < 64) {  // dtype detector: sample even u16s of random-normal weights
      int hits = 0;
      for (int k = 0; k < 4; ++k) {
        unsigned short u = wprobe[(t * 4 + k) * 2];
        int e = (u >> 7) & 0xFF;
        if ((u & 0x7FFFu) != 0 && e >= 108 && e <= 128) hits++;
      }
      for (int off = 32; off; off >>= 1) hits += __shfl_down(hits, off);
      if (t == 0) { sflag = (hits < 128) ? 1 : 0; dflag[0] = sflag; }
    }
    __syncthreads();
    int f32 = sflag;
    for (int j = t; j < kAff; j += 256) flags[aff_idx[j]] = 1;
    if (t < kB * kH) {
      int b = t >> 6, h = t & 63;
      float acc = ldf(b_in, h, f32);
      for (int o = 0; o < kObs; ++o)
        acc += ldf(obs, b * kObs + o, f32) * ldf(W_in, o * kH + h, f32);
      projected[t] = acc;
    }
  } else {
    int rep = (blockIdx.x - 1) & 7;
    int base = (blockIdx.x - 1) * 1024 + t;
#pragma unroll
    for (int k = 0; k < 4; ++k) {
      int e = base + k * 256;
      if (e < kE) {
        int d = dst[e];
        atomicAdd(&vbh[(d >> 6) * 8 + rep], 1);
      }
    }
  }
}

// --- pack state: uint(n,h) = bf16(batch0)|bf16(batch1)<<16 ------------------
extern "C" __global__ void k_pack(const void* __restrict__ state,
                                  const int* __restrict__ dflag,
                                  unsigned int* __restrict__ pack) {
  int f32 = dflag[0];
  int i = blockIdx.x * 256 + threadIdx.x;
  if (i < kNH) {
    float v0 = ldf(state, i, f32);
    float v1 = ldf(state, kNH + i, f32);
    pack[i] = f2b(v0) | (f2b(v1) << 16);
  }
}

// --- weight prep: Wt[n][k] bf16, regions: msg[64x64] gate[64x128] cand[64x128]
extern "C" __global__ void k_wprep(const void* __restrict__ W_msg,
                                   const void* __restrict__ W_gate,
                                   const void* __restrict__ W_cand,
                                   const int* __restrict__ dflag,
                                   unsigned short* __restrict__ wt) {
  int f32 = dflag[0];
  int i = blockIdx.x * 256 + threadIdx.x;  // 0..20479
  if (i < 4096) {
    int n = i >> 6, k = i & 63;
    wt[i] = (unsigned short)f2b(ldf(W_msg, k * 64 + n, f32));
  } else if (i < 12288) {
    int j = i - 4096; int n = j >> 7, k = j & 127;
    wt[i] = (unsigned short)f2b(ldf(W_gate, k * 64 + n, f32));
  } else if (i < 20480) {
    int j = i - 12288; int n = j >> 7, k = j & 127;
    wt[i] = (unsigned short)f2b(ldf(W_cand, k * 64 + n, f32));
  }
}

// --- scan virtual-bucket counts -> offsets + cursors ------------------------
extern "C" __global__ void k_vscan(const int* __restrict__ vbh,
                                   int* __restrict__ vb_off,
                                   int* __restrict__ vb_cur) {
  __shared__ int sd[256];
  int t = threadIdx.x;
  int v[25]; int s = 0;
#pragma unroll
  for (int j = 0; j < 25; ++j) {
    int i = t * 25 + j;
    v[j] = (i < kVB) ? vbh[i] : 0;
    s += v[j];
  }
  sd[t] = s;
  __syncthreads();
  for (int off = 1; off < 256; off <<= 1) {
    int x = (t >= off) ? sd[t - off] : 0;
    __syncthreads();
    sd[t] += x;
    __syncthreads();
  }
  int run = sd[t] - s;
#pragma unroll
  for (int j = 0; j < 25; ++j) {
    int i = t * 25 + j;
    if (i < kVB) { vb_off[i] = run; vb_cur[i] = run; run += v[j]; }
  }
  if (t == 255) vb_off[kVB] = run;  // == kE
}

// --- bucket scatter: edge -> its (bucket, XCD-rep) segment, packed u32 ------
extern "C" __global__ void k_bscatter(const int* __restrict__ src,
                                      const int* __restrict__ dst,
                                      int* __restrict__ vb_cur,
                                      unsigned int* __restrict__ edges_tmp) {
  int rep = blockIdx.x & 7;    // == (e>>10)&7 for all this block's edges
  int base = blockIdx.x * 1024 + threadIdx.x;
#pragma unroll
  for (int k = 0; k < 4; ++k) {
    int e = base + k * 256;
    if (e < kE) {
      int d = dst[e];
      int pos = atomicAdd(&vb_cur[(d >> 6) * 8 + rep], 1);
      edges_tmp[pos] = ((unsigned int)(d & 63) << 16) | (unsigned int)src[e];
    }
  }
}

// --- accumulate: one block per 64-node bucket, LDS f32 accumulators ---------
// Replaces binsort+gather: reads the bucket's (unsorted) edge segment and
// LDS-atomic-adds packed neighbor state rows; emits packed bf16 agg.
extern "C" __global__ __launch_bounds__(256) void k_accum(
    const unsigned int* __restrict__ pack,
    const unsigned int* __restrict__ edges_tmp,
    const int* __restrict__ vb_off,
    unsigned int* __restrict__ agg) {
  __shared__ float acc0[64 * 64];   // 16 KB [node_local][h] batch0
  __shared__ float acc1[64 * 64];   // 16 KB batch1
  int t = threadIdx.x, b = blockIdx.x;
  for (int i = t; i < 4096; i += 256) { acc0[i] = 0.f; acc1[i] = 0.f; }
  __syncthreads();
  int beg = vb_off[8 * b], end = vb_off[8 * b + 8];
  int wv = t >> 6, lane = t & 63;
  for (int e = beg + wv * 4; e < end; e += 16) {
    int m = end - e; if (m > 4) m = 4;
    unsigned int ew[4], pkr[4]; int dl[4];
#pragma unroll
    for (int j = 0; j < 4; ++j)
      if (j < m) ew[j] = edges_tmp[e + j];
#pragma unroll
    for (int j = 0; j < 4; ++j)
      if (j < m) { dl[j] = ew[j] >> 16; pkr[j] = pack[(ew[j] & 0xffffu) * 64 + lane]; }
#pragma unroll
    for (int j = 0; j < 4; ++j)
      if (j < m) {
        atomicAdd(&acc0[dl[j] * 64 + lane], lo16(pkr[j]));
        atomicAdd(&acc1[dl[j] * 64 + lane], hi16(pkr[j]));
      }
  }
  __syncthreads();
  for (int i = t; i < 4096; i += 256) {
    int nl = i >> 6, h = i & 63;
    int n = b * 64 + nl;
    if (n < kN) agg[n * 64 + h] = f2b(acc0[nl * 64 + h]) | (f2b(acc1[nl * 64 + h]) << 16);
  }
}

// --- update (MFMA): msg = agg@W_msg (+inject), GRU gate/cand, next_state ----
// Block: 32 nodes x 2 batches = 64 M-rows. Wave w owns rows [16w,16w+16).
// X LDS [64][136]: cols 0-63 state bf16, cols 64-127 agg -> combined.
// A-frag: lane holds A[m=lane&15][k=(lane>>4)*8+j]; B-frag: B[k][n=lane&15];
// C: col=lane&15, row=(lane>>4)*4+reg (verified mappings, learn_hip m89/m91).
extern "C" __global__ __launch_bounds__(256) void k_update(
    const void* __restrict__ state,
    const unsigned short* __restrict__ wt,   // prepped bf16 Wt msg|gate|cand
    const void* __restrict__ b_gate,
    const void* __restrict__ b_cand,
    const unsigned int* __restrict__ agg,
    const int* __restrict__ flags,
    const float* __restrict__ projected,
    const int* __restrict__ dflag,
    void* __restrict__ out) {
  __shared__ unsigned short lx[64 * 136];     // 17408 B
  __shared__ unsigned short lwt[22016];       // 44032 B: msg@0(72/row) gate@4608 cand@13312(136/row)
  __shared__ float sbias[128];                // gate 0-63 | cand 64-127
  __shared__ float sproj[128];
  __shared__ int   sfl[32];
  int f32 = dflag[0];
  int t = threadIdx.x;
  int nd0 = blockIdx.x * 32;

  // stage weights (u32 = bf16 pair, k-contiguous)
  const unsigned int* w32 = (const unsigned int*)wt;
  for (int i = t; i < 2048; i += 256) {                 // msg
    int n = i >> 5, k2 = i & 31;
    *(unsigned int*)&lwt[n * 72 + 2 * k2] = w32[i];
  }
  for (int i = t; i < 4096; i += 256) {                 // gate
    int n = i >> 6, k2 = i & 63;
    *(unsigned int*)&lwt[4608 + n * 136 + 2 * k2] = w32[2048 + i];
  }
  for (int i = t; i < 4096; i += 256) {                 // cand
    int n = i >> 6, k2 = i & 63;
    *(unsigned int*)&lwt[13312 + n * 136 + 2 * k2] = w32[6144 + i];
  }
  // stage state bf16 -> X cols 0-63
  for (int i = t; i < 4096; i += 256) {
    int row = i >> 6, col = i & 63;
    int ndg = min(nd0 + (row >> 1), kN - 1), b = row & 1;
    lx[row * 136 + col] = (unsigned short)f2b(ldf(state, b * kNH + ndg * 64 + col, f32));
  }
  // stage agg (packed both batches) -> X cols 64-127
  for (int i = t; i < 2048; i += 256) {
    int ndl = i >> 6, col = i & 63;
    unsigned int ag = agg[min(nd0 + ndl, kN - 1) * 64 + col];
    lx[(2 * ndl) * 136 + 64 + col]     = (unsigned short)(ag & 0xffffu);
    lx[(2 * ndl + 1) * 136 + 64 + col] = (unsigned short)(ag >> 16);
  }
  if (t < 64) sbias[t] = ldf(b_gate, t, f32);
  else if (t < 128) sbias[t] = ldf(b_cand, t - 64, f32);
  else sproj[t - 128] = projected[t - 128];
  if (t < 32) sfl[t] = (nd0 + t < kN) ? flags[nd0 + t] : 0;
  __syncthreads();

  int w = t >> 6, lane = t & 63;
  int q = lane >> 4, l15 = lane & 15;
  int rowb = w * 16;

  // --- msg phase: C[16x64] = agg[16x64] @ W_msg[64x64] ---
  short8_t a0 = *(const short8_t*)&lx[(rowb + l15) * 136 + 64 + q * 8];
  short8_t a1 = *(const short8_t*)&lx[(rowb + l15) * 136 + 96 + q * 8];
  f32x4_t msgc[4];
#pragma unroll
  for (int ct = 0; ct < 4; ++ct) {
    f32x4_t acc = {0.f, 0.f, 0.f, 0.f};
    short8_t b0 = *(const short8_t*)&lwt[(ct * 16 + l15) * 72 + q * 8];
    short8_t b1 = *(const short8_t*)&lwt[(ct * 16 + l15) * 72 + 32 + q * 8];
    acc = __builtin_amdgcn_mfma_f32_16x16x32_bf16(a0, b0, acc, 0, 0, 0);
    acc = __builtin_amdgcn_mfma_f32_16x16x32_bf16(a1, b1, acc, 0, 0, 0);
    msgc[ct] = acc;
  }
  // combined = msg + inject -> back into X cols 64-127 (own strip rows only)
#pragma unroll
  for (int ct = 0; ct < 4; ++ct) {
    int col = ct * 16 + l15;
    float pj0 = sproj[col], pj1 = sproj[64 + col];
#pragma unroll
    for (int r = 0; r < 4; ++r) {
      int row = rowb + q * 4 + r;
      int ndl = row >> 1, b = row & 1;
      float inj = sfl[ndl] ? (b ? pj1 : pj0) : 0.f;
      lx[row * 136 + 64 + col] = (unsigned short)f2b(msgc[ct][r] + inj);
    }
  }

  // --- gate/cand phase: K=128 over [state | combined] ---
  short8_t xa[4];
#pragma unroll
  for (int ks = 0; ks < 4; ++ks)
    xa[ks] = *(const short8_t*)&lx[(rowb + l15) * 136 + ks * 32 + q * 8];
#pragma unroll
  for (int ct = 0; ct < 4; ++ct) {
    f32x4_t accg = {0.f, 0.f, 0.f, 0.f}, accc = {0.f, 0.f, 0.f, 0.f};
#pragma unroll
    for (int ks = 0; ks < 4; ++ks) {
      short8_t bg = *(const short8_t*)&lwt[4608 + (ct * 16 + l15) * 136 + ks * 32 + q * 8];
      short8_t bc = *(const short8_t*)&lwt[13312 + (ct * 16 + l15) * 136 + ks * 32 + q * 8];
      accg = __builtin_amdgcn_mfma_f32_16x16x32_bf16(xa[ks], bg, accg, 0, 0, 0);
      accc = __builtin_amdgcn_mfma_f32_16x16x32_bf16(xa[ks], bc, accc, 0, 0, 0);
    }
    int col = ct * 16 + l15;
    float bgv = sbias[col], bcv = sbias[64 + col];
#pragma unroll
    for (int r = 0; r < 4; ++r) {
      int row = rowb + q * 4 + r;
      int nd = nd0 + (row >> 1), b = row & 1;
      if (nd >= kN) continue;
      float z  = 1.f / (1.f + __expf(-(accg[r] + bgv)));
      float cd = tanhf(accc[r] + bcv);
      float sv = ldf(state, b * kNH + nd * 64 + col, f32);
      float ns = (1.f - z) * sv + z * cd;
      stf(out, kOutOff + b * kNH + nd * 64 + col, ns, f32);
    }
  }
}

// --- readout: mean-pool efferent, tanh decode, policy heads -----------------
extern "C" __global__ void k_readout(const void* __restrict__ W_dec,
                                     const void* __restrict__ b_dec,
                                     const void* __restrict__ W_mean,
                                     const void* __restrict__ b_mean,
                                     const void* __restrict__ W_ls,
                                     const void* __restrict__ b_ls,
                                     const int* __restrict__ eff_idx,
                                     const int* __restrict__ dflag,
                                     void* __restrict__ out) {
  __shared__ float part[8][64];
  __shared__ float ro[128], dec[128];
  int f32 = dflag[0];
  int t = threadIdx.x;          // 512 threads = 8 waves
  int wv = t >> 6, lane = t & 63;
  int b = wv >> 2, g = wv & 3;  // wave -> (batch, quarter of eff list)
  float acc = 0.f;
#pragma unroll 4
  for (int i = 0; i < 64; ++i) {
    int n = eff_idx[g * 64 + i];
    acc += ldf(out, kOutOff + b * kNH + n * 64 + lane, f32);
  }
  part[wv][lane] = acc;
  __syncthreads();
  if (t < 128) {
    int bb = t >> 6, h = t & 63;
    float s = part[bb * 4 + 0][h] + part[bb * 4 + 1][h] +
              part[bb * 4 + 2][h] + part[bb * 4 + 3][h];
    ro[t] = s * (1.f / kEff);
  }
  __syncthreads();
  if (t < 128) {
    int bb = t >> 6, h = t & 63;
    float d = ldf(b_dec, h, f32);
    for (int k = 0; k < 64; ++k) d += ro[bb * 64 + k] * ldf(W_dec, k * 64 + h, f32);
    dec[t] = tanhf(d);
  }
  __syncthreads();
  if (t < kB * kA) {
    int bb = t / kA, a = t % kA;
    float m = ldf(b_mean, a, f32), l = ldf(b_ls, a, f32);
    for (int k = 0; k < 64; ++k) {
      float dv = dec[bb * 64 + k];
      m += dv * ldf(W_mean, k * kA + a, f32);
      l += dv * ldf(W_ls, k * kA + a, f32);
    }
    l = fminf(fmaxf(l, -5.f), 2.f);
    stf(out, t, m, f32);            // mean[2][18]
    stf(out, kB * kA + t, l, f32);  // log_std[2][18]
  }
}

extern "C" void kernel_launch(void* const* d_in, const int* in_sizes, int n_in,
                              void* d_out, int out_size, void* d_ws, size_t ws_size,
                              hipStream_t stream) {
  (void)in_sizes; (void)n_in; (void)out_size; (void)ws_size;
  const void* obs    = d_in[0];
  const void* state  = d_in[1];
  const void* W_in   = d_in[2];
  const void* b_in   = d_in[3];
  const void* W_msg  = d_in[4];
  const void* W_gate = d_in[5];
  const void* b_gate = d_in[6];
  const void* W_cand = d_in[7];
  const void* b_cand = d_in[8];
  const void* W_dec  = d_in[9];
  const void* b_dec  = d_in[10];
  const void* W_mean = d_in[11];
  const void* b_mean = d_in[12];
  const void* W_ls   = d_in[13];
  const void* b_ls   = d_in[14];
  const int* src = (const int*)d_in[15];
  const int* dst = (const int*)d_in[16];
  const int* aff = (const int*)d_in[17];
  const int* eff = (const int*)d_in[18];

  // workspace layout (~30 MB)
  int* wsp        = (int*)d_ws;
  int* flags      = wsp;                   // [N]        (memset 0)
  int* vbh        = flags + kN;            // [6272]     (memset 0)
  int* vb_off     = vbh + 6272;            // [kVB+1] -> pad 6272
  int* vb_cur     = vb_off + 6272;         // [6256] -> pad 6272
  int* dflag      = vb_cur + 6272;         // [16]
  float* projected = (float*)(dflag + 16);          // [128]
  unsigned int* edges_tmp = (unsigned int*)(projected + 128);  // [E]
  unsigned int* pk  = edges_tmp + kE;               // [N*H]
  unsigned int* agg = pk + kNH;                     // [N*H]
  unsigned short* wt = (unsigned short*)(agg + kNH);  // [20480] bf16

  hipMemsetAsync(flags, 0, size_t(kN + 6272) * sizeof(int), stream);  // flags+vbh
  k_front<<<1 + kHistBlocks, 256, 0, stream>>>(
      (const unsigned short*)W_cand, obs, W_in, b_in, aff, dst,
      dflag, flags, projected, vbh);
  k_pack<<<(kNH + 255) / 256, 256, 0, stream>>>(state, dflag, pk);
  k_wprep<<<80, 256, 0, stream>>>(W_msg, W_gate, W_cand, dflag, wt);
  k_vscan<<<1, 256, 0, stream>>>(vbh, vb_off, vb_cur);
  k_bscatter<<<kHistBlocks, 256, 0, stream>>>(src, dst, vb_cur, edges_tmp);
  k_accum<<<kNB, 256, 0, stream>>>(pk, edges_tmp, vb_off, agg);
  k_update<<<(kN + 31) / 32, 256, 0, stream>>>(state, wt, b_gate, b_cand,
                                               agg, flags, projected, dflag, d_out);
  k_readout<<<1, 512, 0, stream>>>(W_dec, b_dec, W_mean, b_mean, W_ls, b_ls, eff,
                                   dflag, d_out);
}

// Round 8
// 1127.104 us; speedup vs baseline: 1.0506x; 1.0506x over previous
//
#include <hip/hip_runtime.h>
#include <hip/hip_bf16.h>

// Problem constants (WholeBrainRateModel)
constexpr int kN   = 50000;    // nodes
constexpr int kH   = 64;       // hidden
constexpr int kB   = 2;        // batch
constexpr int kE   = 1000000;  // edges
constexpr int kObs = 128;
constexpr int kA   = 18;
constexpr int kAff = 512;
constexpr int kEff = 256;
constexpr int kNH  = kN * kH;
constexpr int kOutOff = 2 * kB * kA;  // 72 elements: mean+log_std before next_state
constexpr int kHistBlocks = (kE + 1023) / 1024;  // 977 (4 edges/thread, 256 thr)
constexpr int kNB  = 782;        // node buckets (64 nodes each), 782*64 >= 50000
constexpr int kVB  = kNB * 8;    // 6256 (bucket, XCD-rep) segments
constexpr int kCap = 320;        // capacity per segment (mean 160, +12.6 sigma)

typedef __attribute__((ext_vector_type(8))) short short8_t;  // 8 bf16 (4 VGPRs)
typedef __attribute__((ext_vector_type(4))) float f32x4_t;

// dtype-adaptive load/store (flag==1 -> float32 buffers, else bf16).
__device__ __forceinline__ float ldf(const void* p, int i, int f32) {
  if (f32) return ((const float*)p)[i];
  unsigned short u = ((const unsigned short*)p)[i];
  union { unsigned int x; float f; } v; v.x = ((unsigned int)u) << 16; return v.f;
}
__device__ __forceinline__ void stf(void* p, int i, float val, int f32) {
  if (f32) ((float*)p)[i] = val;
  else ((__hip_bfloat16*)p)[i] = __float2bfloat16(val);
}
__device__ __forceinline__ float lo16(unsigned int w) {
  union { unsigned int i; float f; } v; v.i = w << 16; return v.f;
}
__device__ __forceinline__ float hi16(unsigned int w) {
  union { unsigned int i; float f; } v; v.i = w & 0xffff0000u; return v.f;
}
__device__ __forceinline__ unsigned int f2b(float f) {  // rne bf16 bits
  union { float f; unsigned int u; } v; v.f = f;
  unsigned int r = v.u + 0x7fffu + ((v.u >> 16) & 1u);
  return r >> 16;
}

// --- front (1 block): dtype-detect + afferent flags + obs@W_in + cursor init
extern "C" __global__ void k_front(const unsigned short* __restrict__ wprobe,
                                   const void* __restrict__ obs,
                                   const void* __restrict__ W_in,
                                   const void* __restrict__ b_in,
                                   const int* __restrict__ aff_idx,
                                   int* __restrict__ dflag,
                                   int* __restrict__ flags,
                                   float* __restrict__ projected,
                                   int* __restrict__ vb_cur) {
  int t = threadIdx.x;
  __shared__ int sflag;
  if (t < 64) {  // dtype detector: sample even u16s of random-normal weights
    int hits = 0;
    for (int k = 0; k < 4; ++k) {
      unsigned short u = wprobe[(t * 4 + k) * 2];
      int e = (u >> 7) & 0xFF;
      if ((u & 0x7FFFu) != 0 && e >= 108 && e <= 128) hits++;
    }
    for (int off = 32; off; off >>= 1) hits += __shfl_down(hits, off);
    if (t == 0) { sflag = (hits < 128) ? 1 : 0; dflag[0] = sflag; }
  }
  for (int i = t; i < kVB; i += 256) vb_cur[i] = i * kCap;  // segment bases
  __syncthreads();
  int f32 = sflag;
  for (int j = t; j < kAff; j += 256) flags[aff_idx[j]] = 1;
  if (t < kB * kH) {
    int b = t >> 6, h = t & 63;
    float acc = ldf(b_in, h, f32);
    for (int o = 0; o < kObs; ++o)
      acc += ldf(obs, b * kObs + o, f32) * ldf(W_in, o * kH + h, f32);
    projected[t] = acc;
  }
}

// --- pack state: uint(n,h) = bf16(batch0)|bf16(batch1)<<16 ------------------
extern "C" __global__ void k_pack(const void* __restrict__ state,
                                  const int* __restrict__ dflag,
                                  unsigned int* __restrict__ pack) {
  int f32 = dflag[0];
  int i = blockIdx.x * 256 + threadIdx.x;
  if (i < kNH) {
    float v0 = ldf(state, i, f32);
    float v1 = ldf(state, kNH + i, f32);
    pack[i] = f2b(v0) | (f2b(v1) << 16);
  }
}

// --- weight prep: Wt[n][k] bf16, regions: msg[64x64] gate[64x128] cand[64x128]
extern "C" __global__ void k_wprep(const void* __restrict__ W_msg,
                                   const void* __restrict__ W_gate,
                                   const void* __restrict__ W_cand,
                                   const int* __restrict__ dflag,
                                   unsigned short* __restrict__ wt) {
  int f32 = dflag[0];
  int i = blockIdx.x * 256 + threadIdx.x;  // 0..20479
  if (i < 4096) {
    int n = i >> 6, k = i & 63;
    wt[i] = (unsigned short)f2b(ldf(W_msg, k * 64 + n, f32));
  } else if (i < 12288) {
    int j = i - 4096; int n = j >> 7, k = j & 127;
    wt[i] = (unsigned short)f2b(ldf(W_gate, k * 64 + n, f32));
  } else if (i < 20480) {
    int j = i - 12288; int n = j >> 7, k = j & 127;
    wt[i] = (unsigned short)f2b(ldf(W_cand, k * 64 + n, f32));
  }
}

// --- bucket scatter: edge -> fixed-capacity (bucket, XCD-rep) segment -------
// rep = blockIdx&7: all writers of one segment share an XCD under round-robin
// dispatch, so L2 assembles full lines. Capacity clamp can only drop edges
// (P ~ 1e-20 per segment for uniform dst), never corrupt.
extern "C" __global__ void k_bscatter(const int* __restrict__ src,
                                      const int* __restrict__ dst,
                                      int* __restrict__ vb_cur,
                                      unsigned int* __restrict__ edges_tmp) {
  int rep = blockIdx.x & 7;
  int base = blockIdx.x * 1024 + threadIdx.x;
#pragma unroll
  for (int k = 0; k < 4; ++k) {
    int e = base + k * 256;
    if (e < kE) {
      int d = dst[e];
      int vb = (d >> 6) * 8 + rep;
      int pos = atomicAdd(&vb_cur[vb], 1);
      if (pos < vb * kCap + kCap)
        edges_tmp[pos] = ((unsigned int)(d & 63) << 16) | (unsigned int)src[e];
    }
  }
}

// --- accumulate: one block per 64-node bucket, 8 waves <-> 8 rep segments ---
// 16-deep gather pipeline per wave for MLP; LDS f32 atomic accumulate.
extern "C" __global__ __launch_bounds__(512) void k_accum(
    const unsigned int* __restrict__ pack,
    const unsigned int* __restrict__ edges_tmp,
    const int* __restrict__ vb_cur,
    unsigned int* __restrict__ agg) {
  __shared__ float acc0[64 * 64];   // 16 KB [node_local][h] batch0
  __shared__ float acc1[64 * 64];   // 16 KB batch1
  int t = threadIdx.x, b = blockIdx.x;
  for (int i = t; i < 4096; i += 512) { acc0[i] = 0.f; acc1[i] = 0.f; }
  __syncthreads();
  int wv = t >> 6, lane = t & 63;
  int vb = b * 8 + wv, base = vb * kCap;
  int cnt = vb_cur[vb] - base;
  if (cnt > kCap) cnt = kCap;
  int e0 = 0;
  for (; e0 + 16 <= cnt; e0 += 16) {
    const unsigned int* ep = edges_tmp + base + e0;
    unsigned int ew[16];
#pragma unroll
    for (int j = 0; j < 16; ++j) ew[j] = ep[j];
    unsigned int pr[16];
#pragma unroll
    for (int j = 0; j < 16; ++j) pr[j] = pack[(ew[j] & 0xffffu) * 64 + lane];
#pragma unroll
    for (int j = 0; j < 16; ++j) {
      int dl = ew[j] >> 16;
      atomicAdd(&acc0[dl * 64 + lane], lo16(pr[j]));
      atomicAdd(&acc1[dl * 64 + lane], hi16(pr[j]));
    }
  }
  for (; e0 < cnt; ++e0) {
    unsigned int ew = edges_tmp[base + e0];
    unsigned int pr = pack[(ew & 0xffffu) * 64 + lane];
    int dl = ew >> 16;
    atomicAdd(&acc0[dl * 64 + lane], lo16(pr));
    atomicAdd(&acc1[dl * 64 + lane], hi16(pr));
  }
  __syncthreads();
  for (int i = t; i < 4096; i += 512) {
    int nl = i >> 6, h = i & 63;
    int n = b * 64 + nl;
    if (n < kN) agg[n * 64 + h] = f2b(acc0[nl * 64 + h]) | (f2b(acc1[nl * 64 + h]) << 16);
  }
}

// --- update (MFMA): msg = agg@W_msg (+inject), GRU gate/cand, next_state ----
// Block: 32 nodes x 2 batches = 64 M-rows. Wave w owns rows [16w,16w+16).
// X LDS [64][136]: cols 0-63 state bf16, cols 64-127 agg -> combined.
// A-frag: lane holds A[m=lane&15][k=(lane>>4)*8+j]; B-frag: B[k][n=lane&15];
// C: col=lane&15, row=(lane>>4)*4+reg (verified mappings, learn_hip m89/m91).
extern "C" __global__ __launch_bounds__(256) void k_update(
    const void* __restrict__ state,
    const unsigned short* __restrict__ wt,   // prepped bf16 Wt msg|gate|cand
    const void* __restrict__ b_gate,
    const void* __restrict__ b_cand,
    const unsigned int* __restrict__ agg,
    const int* __restrict__ flags,
    const float* __restrict__ projected,
    const int* __restrict__ dflag,
    void* __restrict__ out) {
  __shared__ unsigned short lx[64 * 136];     // 17408 B
  __shared__ unsigned short lwt[22016];       // 44032 B: msg@0(72/row) gate@4608 cand@13312(136/row)
  __shared__ float sbias[128];                // gate 0-63 | cand 64-127
  __shared__ float sproj[128];
  __shared__ int   sfl[32];
  int f32 = dflag[0];
  int t = threadIdx.x;
  int nd0 = blockIdx.x * 32;

  // stage weights (u32 = bf16 pair, k-contiguous)
  const unsigned int* w32 = (const unsigned int*)wt;
  for (int i = t; i < 2048; i += 256) {                 // msg
    int n = i >> 5, k2 = i & 31;
    *(unsigned int*)&lwt[n * 72 + 2 * k2] = w32[i];
  }
  for (int i = t; i < 4096; i += 256) {                 // gate
    int n = i >> 6, k2 = i & 63;
    *(unsigned int*)&lwt[4608 + n * 136 + 2 * k2] = w32[2048 + i];
  }
  for (int i = t; i < 4096; i += 256) {                 // cand
    int n = i >> 6, k2 = i & 63;
    *(unsigned int*)&lwt[13312 + n * 136 + 2 * k2] = w32[6144 + i];
  }
  // stage state bf16 -> X cols 0-63
  for (int i = t; i < 4096; i += 256) {
    int row = i >> 6, col = i & 63;
    int ndg = min(nd0 + (row >> 1), kN - 1), b = row & 1;
    lx[row * 136 + col] = (unsigned short)f2b(ldf(state, b * kNH + ndg * 64 + col, f32));
  }
  // stage agg (packed both batches) -> X cols 64-127
  for (int i = t; i < 2048; i += 256) {
    int ndl = i >> 6, col = i & 63;
    unsigned int ag = agg[min(nd0 + ndl, kN - 1) * 64 + col];
    lx[(2 * ndl) * 136 + 64 + col]     = (unsigned short)(ag & 0xffffu);
    lx[(2 * ndl + 1) * 136 + 64 + col] = (unsigned short)(ag >> 16);
  }
  if (t < 64) sbias[t] = ldf(b_gate, t, f32);
  else if (t < 128) sbias[t] = ldf(b_cand, t - 64, f32);
  else sproj[t - 128] = projected[t - 128];
  if (t < 32) sfl[t] = (nd0 + t < kN) ? flags[nd0 + t] : 0;
  __syncthreads();

  int w = t >> 6, lane = t & 63;
  int q = lane >> 4, l15 = lane & 15;
  int rowb = w * 16;

  // --- msg phase: C[16x64] = agg[16x64] @ W_msg[64x64] ---
  short8_t a0 = *(const short8_t*)&lx[(rowb + l15) * 136 + 64 + q * 8];
  short8_t a1 = *(const short8_t*)&lx[(rowb + l15) * 136 + 96 + q * 8];
  f32x4_t msgc[4];
#pragma unroll
  for (int ct = 0; ct < 4; ++ct) {
    f32x4_t acc = {0.f, 0.f, 0.f, 0.f};
    short8_t b0 = *(const short8_t*)&lwt[(ct * 16 + l15) * 72 + q * 8];
    short8_t b1 = *(const short8_t*)&lwt[(ct * 16 + l15) * 72 + 32 + q * 8];
    acc = __builtin_amdgcn_mfma_f32_16x16x32_bf16(a0, b0, acc, 0, 0, 0);
    acc = __builtin_amdgcn_mfma_f32_16x16x32_bf16(a1, b1, acc, 0, 0, 0);
    msgc[ct] = acc;
  }
  // combined = msg + inject -> back into X cols 64-127 (own strip rows only)
#pragma unroll
  for (int ct = 0; ct < 4; ++ct) {
    int col = ct * 16 + l15;
    float pj0 = sproj[col], pj1 = sproj[64 + col];
#pragma unroll
    for (int r = 0; r < 4; ++r) {
      int row = rowb + q * 4 + r;
      int ndl = row >> 1, b = row & 1;
      float inj = sfl[ndl] ? (b ? pj1 : pj0) : 0.f;
      lx[row * 136 + 64 + col] = (unsigned short)f2b(msgc[ct][r] + inj);
    }
  }

  // --- gate/cand phase: K=128 over [state | combined] ---
  short8_t xa[4];
#pragma unroll
  for (int ks = 0; ks < 4; ++ks)
    xa[ks] = *(const short8_t*)&lx[(rowb + l15) * 136 + ks * 32 + q * 8];
#pragma unroll
  for (int ct = 0; ct < 4; ++ct) {
    f32x4_t accg = {0.f, 0.f, 0.f, 0.f}, accc = {0.f, 0.f, 0.f, 0.f};
#pragma unroll
    for (int ks = 0; ks < 4; ++ks) {
      short8_t bg = *(const short8_t*)&lwt[4608 + (ct * 16 + l15) * 136 + ks * 32 + q * 8];
      short8_t bc = *(const short8_t*)&lwt[13312 + (ct * 16 + l15) * 136 + ks * 32 + q * 8];
      accg = __builtin_amdgcn_mfma_f32_16x16x32_bf16(xa[ks], bg, accg, 0, 0, 0);
      accc = __builtin_amdgcn_mfma_f32_16x16x32_bf16(xa[ks], bc, accc, 0, 0, 0);
    }
    int col = ct * 16 + l15;
    float bgv = sbias[col], bcv = sbias[64 + col];
#pragma unroll
    for (int r = 0; r < 4; ++r) {
      int row = rowb + q * 4 + r;
      int nd = nd0 + (row >> 1), b = row & 1;
      if (nd >= kN) continue;
      float z  = 1.f / (1.f + __expf(-(accg[r] + bgv)));
      float cd = tanhf(accc[r] + bcv);
      float sv = ldf(state, b * kNH + nd * 64 + col, f32);
      float ns = (1.f - z) * sv + z * cd;
      stf(out, kOutOff + b * kNH + nd * 64 + col, ns, f32);
    }
  }
}

// --- readout: mean-pool efferent, tanh decode, policy heads -----------------
extern "C" __global__ void k_readout(const void* __restrict__ W_dec,
                                     const void* __restrict__ b_dec,
                                     const void* __restrict__ W_mean,
                                     const void* __restrict__ b_mean,
                                     const void* __restrict__ W_ls,
                                     const void* __restrict__ b_ls,
                                     const int* __restrict__ eff_idx,
                                     const int* __restrict__ dflag,
                                     void* __restrict__ out) {
  __shared__ float part[8][64];
  __shared__ float ro[128], dec[128];
  int f32 = dflag[0];
  int t = threadIdx.x;          // 512 threads = 8 waves
  int wv = t >> 6, lane = t & 63;
  int b = wv >> 2, g = wv & 3;  // wave -> (batch, quarter of eff list)
  float acc = 0.f;
#pragma unroll 4
  for (int i = 0; i < 64; ++i) {
    int n = eff_idx[g * 64 + i];
    acc += ldf(out, kOutOff + b * kNH + n * 64 + lane, f32);
  }
  part[wv][lane] = acc;
  __syncthreads();
  if (t < 128) {
    int bb = t >> 6, h = t & 63;
    float s = part[bb * 4 + 0][h] + part[bb * 4 + 1][h] +
              part[bb * 4 + 2][h] + part[bb * 4 + 3][h];
    ro[t] = s * (1.f / kEff);
  }
  __syncthreads();
  if (t < 128) {
    int bb = t >> 6, h = t & 63;
    float d = ldf(b_dec, h, f32);
    for (int k = 0; k < 64; ++k) d += ro[bb * 64 + k] * ldf(W_dec, k * 64 + h, f32);
    dec[t] = tanhf(d);
  }
  __syncthreads();
  if (t < kB * kA) {
    int bb = t / kA, a = t % kA;
    float m = ldf(b_mean, a, f32), l = ldf(b_ls, a, f32);
    for (int k = 0; k < 64; ++k) {
      float dv = dec[bb * 64 + k];
      m += dv * ldf(W_mean, k * kA + a, f32);
      l += dv * ldf(W_ls, k * kA + a, f32);
    }
    l = fminf(fmaxf(l, -5.f), 2.f);
    stf(out, t, m, f32);            // mean[2][18]
    stf(out, kB * kA + t, l, f32);  // log_std[2][18]
  }
}

extern "C" void kernel_launch(void* const* d_in, const int* in_sizes, int n_in,
                              void* d_out, int out_size, void* d_ws, size_t ws_size,
                              hipStream_t stream) {
  (void)in_sizes; (void)n_in; (void)out_size; (void)ws_size;
  const void* obs    = d_in[0];
  const void* state  = d_in[1];
  const void* W_in   = d_in[2];
  const void* b_in   = d_in[3];
  const void* W_msg  = d_in[4];
  const void* W_gate = d_in[5];
  const void* b_gate = d_in[6];
  const void* W_cand = d_in[7];
  const void* b_cand = d_in[8];
  const void* W_dec  = d_in[9];
  const void* b_dec  = d_in[10];
  const void* W_mean = d_in[11];
  const void* b_mean = d_in[12];
  const void* W_ls   = d_in[13];
  const void* b_ls   = d_in[14];
  const int* src = (const int*)d_in[15];
  const int* dst = (const int*)d_in[16];
  const int* aff = (const int*)d_in[17];
  const int* eff = (const int*)d_in[18];

  // workspace layout (~34 MB)
  int* wsp        = (int*)d_ws;
  int* flags      = wsp;                   // [N]      (memset 0)
  int* vb_cur     = flags + kN;            // [kVB] -> pad 6272
  int* dflag      = vb_cur + 6272;         // [16]
  float* projected = (float*)(dflag + 16);          // [128]
  unsigned int* edges_tmp = (unsigned int*)(projected + 128);  // [kVB*kCap] ~8 MB
  unsigned int* pk  = edges_tmp + kVB * kCap;       // [N*H] 12.8 MB
  unsigned int* agg = pk + kNH;                     // [N*H] 12.8 MB
  unsigned short* wt = (unsigned short*)(agg + kNH);  // [20480] bf16

  hipMemsetAsync(flags, 0, size_t(kN) * sizeof(int), stream);
  k_front<<<1, 256, 0, stream>>>((const unsigned short*)W_cand, obs, W_in, b_in,
                                 aff, dflag, flags, projected, vb_cur);
  k_pack<<<(kNH + 255) / 256, 256, 0, stream>>>(state, dflag, pk);
  k_wprep<<<80, 256, 0, stream>>>(W_msg, W_gate, W_cand, dflag, wt);
  k_bscatter<<<kHistBlocks, 256, 0, stream>>>(src, dst, vb_cur, edges_tmp);
  k_accum<<<kNB, 512, 0, stream>>>(pk, edges_tmp, vb_cur, agg);
  k_update<<<(kN + 31) / 32, 256, 0, stream>>>(state, wt, b_gate, b_cand,
                                               agg, flags, projected, dflag, d_out);
  k_readout<<<1, 512, 0, stream>>>(W_dec, b_dec, W_mean, b_mean, W_ls, b_ls, eff,
                                   dflag, d_out);
}

// Round 9
// 367.835 us; speedup vs baseline: 3.2192x; 3.0642x over previous
//
#include <hip/hip_runtime.h>
#include <hip/hip_bf16.h>

// Problem constants (WholeBrainRateModel)
constexpr int kN   = 50000;    // nodes
constexpr int kH   = 64;       // hidden
constexpr int kB   = 2;        // batch
constexpr int kE   = 1000000;  // edges
constexpr int kObs = 128;
constexpr int kA   = 18;
constexpr int kAff = 512;
constexpr int kEff = 256;
constexpr int kNH  = kN * kH;
constexpr int kOutOff = 2 * kB * kA;  // 72 elements: mean+log_std before next_state
constexpr int kHistBlocks = (kE + 1023) / 1024;  // 977 (4 edges/thread, 256 thr)
constexpr int kR   = 8;              // XCD-keyed regions
constexpr int kN8  = kR * kN;        // 400000 region-major CSR keys
constexpr int kScanB8 = (kN8 + 1023) / 1024;  // 391

typedef __attribute__((ext_vector_type(8))) short short8_t;  // 8 bf16 (4 VGPRs)
typedef __attribute__((ext_vector_type(4))) float f32x4_t;

// dtype-adaptive load/store (flag==1 -> float32 buffers, else bf16).
__device__ __forceinline__ float ldf(const void* p, int i, int f32) {
  if (f32) return ((const float*)p)[i];
  unsigned short u = ((const unsigned short*)p)[i];
  union { unsigned int x; float f; } v; v.x = ((unsigned int)u) << 16; return v.f;
}
__device__ __forceinline__ void stf(void* p, int i, float val, int f32) {
  if (f32) ((float*)p)[i] = val;
  else ((__hip_bfloat16*)p)[i] = __float2bfloat16(val);
}
__device__ __forceinline__ float lo16(unsigned int w) {
  union { unsigned int i; float f; } v; v.i = w << 16; return v.f;
}
__device__ __forceinline__ float hi16(unsigned int w) {
  union { unsigned int i; float f; } v; v.i = w & 0xffff0000u; return v.f;
}
__device__ __forceinline__ unsigned int f2b(float f) {  // rne bf16 bits
  union { float f; unsigned int u; } v; v.f = f;
  unsigned int r = v.u + 0x7fffu + ((v.u >> 16) & 1u);
  return r >> 16;
}

// --- fused: block0 = detect + flags + obs@W_in; rest = region-keyed hist ----
// rep = (blockIdx-1)&7: all histogram writers of region r share one XCD under
// round-robin dispatch -> deg8 counter lines stay in that XCD's L2.
extern "C" __global__ void k_front(const unsigned short* __restrict__ wprobe,
                                   const void* __restrict__ obs,
                                   const void* __restrict__ W_in,
                                   const void* __restrict__ b_in,
                                   const int* __restrict__ aff_idx,
                                   const int* __restrict__ dst,
                                   int* __restrict__ dflag,
                                   int* __restrict__ flags,
                                   float* __restrict__ projected,
                                   int* __restrict__ deg8) {
  int t = threadIdx.x;
  if (blockIdx.x == 0) {
    __shared__ int sflag;
    if (t < 64) {  // dtype detector: sample even u16s of random-normal weights
      int hits = 0;
      for (int k = 0; k < 4; ++k) {
        unsigned short u = wprobe[(t * 4 + k) * 2];
        int e = (u >> 7) & 0xFF;
        if ((u & 0x7FFFu) != 0 && e >= 108 && e <= 128) hits++;
      }
      for (int off = 32; off; off >>= 1) hits += __shfl_down(hits, off);
      if (t == 0) { sflag = (hits < 128) ? 1 : 0; dflag[0] = sflag; }
    }
    __syncthreads();
    int f32 = sflag;
    for (int j = t; j < kAff; j += 256) flags[aff_idx[j]] = 1;
    if (t < kB * kH) {
      int b = t >> 6, h = t & 63;
      float acc = ldf(b_in, h, f32);
      for (int o = 0; o < kObs; ++o)
        acc += ldf(obs, b * kObs + o, f32) * ldf(W_in, o * kH + h, f32);
      projected[t] = acc;
    }
  } else {
    int rep = (blockIdx.x - 1) & 7;
    int base = (blockIdx.x - 1) * 1024 + t;
#pragma unroll
    for (int k = 0; k < 4; ++k) {
      int e = base + k * 256;
      if (e < kE) atomicAdd(&deg8[rep * kN + dst[e]], 1);
    }
  }
}

// --- pack state: uint(n,h) = bf16(batch0)|bf16(batch1)<<16 ------------------
extern "C" __global__ void k_pack(const void* __restrict__ state,
                                  const int* __restrict__ dflag,
                                  unsigned int* __restrict__ pack) {
  int f32 = dflag[0];
  int i = blockIdx.x * 256 + threadIdx.x;
  if (i < kNH) {
    float v0 = ldf(state, i, f32);
    float v1 = ldf(state, kNH + i, f32);
    pack[i] = f2b(v0) | (f2b(v1) << 16);
  }
}

// --- weight prep: Wt[n][k] bf16, regions: msg[64x64] gate[64x128] cand[64x128]
extern "C" __global__ void k_wprep(const void* __restrict__ W_msg,
                                   const void* __restrict__ W_gate,
                                   const void* __restrict__ W_cand,
                                   const int* __restrict__ dflag,
                                   unsigned short* __restrict__ wt) {
  int f32 = dflag[0];
  int i = blockIdx.x * 256 + threadIdx.x;  // 0..20479
  if (i < 4096) {
    int n = i >> 6, k = i & 63;
    wt[i] = (unsigned short)f2b(ldf(W_msg, k * 64 + n, f32));
  } else if (i < 12288) {
    int j = i - 4096; int n = j >> 7, k = j & 127;
    wt[i] = (unsigned short)f2b(ldf(W_gate, k * 64 + n, f32));
  } else if (i < 20480) {
    int j = i - 12288; int n = j >> 7, k = j & 127;
    wt[i] = (unsigned short)f2b(ldf(W_cand, k * 64 + n, f32));
  }
}

// --- scan over kN8 region-major keys ----------------------------------------
extern "C" __global__ void k_scan1(const int* __restrict__ deg8,
                                   int* __restrict__ row_off8,
                                   int* __restrict__ partials) {
  __shared__ int sd[256];
  int t = threadIdx.x;
  int base = blockIdx.x * 1024 + t * 4;
  int d0 = (base + 0 < kN8) ? deg8[base + 0] : 0;
  int d1 = (base + 1 < kN8) ? deg8[base + 1] : 0;
  int d2 = (base + 2 < kN8) ? deg8[base + 2] : 0;
  int d3 = (base + 3 < kN8) ? deg8[base + 3] : 0;
  int s4 = d0 + d1 + d2 + d3;
  sd[t] = s4;
  __syncthreads();
  for (int off = 1; off < 256; off <<= 1) {
    int v = (t >= off) ? sd[t - off] : 0;
    __syncthreads();
    sd[t] += v;
    __syncthreads();
  }
  int excl = sd[t] - s4;
  if (t == 255) partials[blockIdx.x] = sd[255];
  if (base + 0 < kN8) row_off8[base + 0] = excl;
  excl += d0;
  if (base + 1 < kN8) row_off8[base + 1] = excl;
  excl += d1;
  if (base + 2 < kN8) row_off8[base + 2] = excl;
  excl += d2;
  if (base + 3 < kN8) row_off8[base + 3] = excl;
}

extern "C" __global__ void k_scan2(int* __restrict__ partials, int* __restrict__ row_off8) {
  if (threadIdx.x == 0) {
    int run = 0;
    for (int i = 0; i < kScanB8; ++i) {
      int v = partials[i];
      partials[i] = run;
      run += v;
    }
    row_off8[kN8] = run;  // == kE
  }
}

extern "C" __global__ void k_scan3(int* __restrict__ row_off8,
                                   const int* __restrict__ partials,
                                   int* __restrict__ cursor8) {
  int i = blockIdx.x * 256 + threadIdx.x;
  if (i < kN8) {
    int v = row_off8[i] + partials[i >> 10];
    row_off8[i] = v;
    cursor8[i] = v;
  }
}

// --- scatter: edge -> region-major CSR slot (region = XCD under heuristic) --
extern "C" __global__ void k_scatter(const int* __restrict__ src,
                                     const int* __restrict__ dst,
                                     int* __restrict__ cursor8,
                                     int* __restrict__ sorted_src) {
  int rep = blockIdx.x & 7;    // == (e>>10)&7 for all this block's edges
  int base = blockIdx.x * 1024 + threadIdx.x;
#pragma unroll
  for (int k = 0; k < 4; ++k) {
    int e = base + k * 256;
    if (e < kE) {
      int pos = atomicAdd(&cursor8[rep * kN + dst[e]], 1);
      sorted_src[pos] = src[e];
    }
  }
}

// --- gather: one wave per node, sum over its 8 region spans -----------------
extern "C" __global__ __launch_bounds__(256) void k_gather(
    const unsigned int* __restrict__ pack,
    const int* __restrict__ row_off8,
    const int* __restrict__ sorted_src,
    unsigned int* __restrict__ agg) {
  int wave = threadIdx.x >> 6, lane = threadIdx.x & 63;
  int n = blockIdx.x * 4 + wave;
  if (n >= kN) return;
  // 16 span boundaries in one parallel load: lane l<16 -> region l&7, +(l>>3)
  int bv = 0;
  if (lane < 16) bv = row_off8[(lane & 7) * kN + n + (lane >> 3)];
  float a0 = 0.f, a1 = 0.f;
#pragma unroll 1
  for (int r = 0; r < 8; ++r) {
    int s = __shfl(bv, r), en = __shfl(bv, r + 8);
    for (int e = s; e < en; e += 4) {
      int m = en - e;
      int i0 = sorted_src[e];
      int i1 = sorted_src[m > 1 ? e + 1 : e];
      int i2 = sorted_src[m > 2 ? e + 2 : e];
      int i3 = sorted_src[m > 3 ? e + 3 : e];
      unsigned int w0 = pack[i0 * 64 + lane];
      unsigned int w1 = pack[i1 * 64 + lane];
      unsigned int w2 = pack[i2 * 64 + lane];
      unsigned int w3 = pack[i3 * 64 + lane];
      a0 += lo16(w0); a1 += hi16(w0);
      if (m > 1) { a0 += lo16(w1); a1 += hi16(w1); }
      if (m > 2) { a0 += lo16(w2); a1 += hi16(w2); }
      if (m > 3) { a0 += lo16(w3); a1 += hi16(w3); }
    }
  }
  agg[n * 64 + lane] = f2b(a0) | (f2b(a1) << 16);
}

// --- update (MFMA): msg = agg@W_msg (+inject), GRU gate/cand, next_state ----
// Block: 32 nodes x 2 batches = 64 M-rows. Wave w owns rows [16w,16w+16).
// X LDS [64][136]: cols 0-63 state bf16, cols 64-127 agg -> combined.
// A-frag: lane holds A[m=lane&15][k=(lane>>4)*8+j]; B-frag: B[k][n=lane&15];
// C: col=lane&15, row=(lane>>4)*4+reg (verified mappings, learn_hip m89/m91).
extern "C" __global__ __launch_bounds__(256) void k_update(
    const void* __restrict__ state,
    const unsigned short* __restrict__ wt,   // prepped bf16 Wt msg|gate|cand
    const void* __restrict__ b_gate,
    const void* __restrict__ b_cand,
    const unsigned int* __restrict__ agg,
    const int* __restrict__ flags,
    const float* __restrict__ projected,
    const int* __restrict__ dflag,
    void* __restrict__ out) {
  __shared__ unsigned short lx[64 * 136];     // 17408 B
  __shared__ unsigned short lwt[22016];       // 44032 B: msg@0(72/row) gate@4608 cand@13312(136/row)
  __shared__ float sbias[128];                // gate 0-63 | cand 64-127
  __shared__ float sproj[128];
  __shared__ int   sfl[32];
  int f32 = dflag[0];
  int t = threadIdx.x;
  int nd0 = blockIdx.x * 32;

  // stage weights (u32 = bf16 pair, k-contiguous)
  const unsigned int* w32 = (const unsigned int*)wt;
  for (int i = t; i < 2048; i += 256) {                 // msg
    int n = i >> 5, k2 = i & 31;
    *(unsigned int*)&lwt[n * 72 + 2 * k2] = w32[i];
  }
  for (int i = t; i < 4096; i += 256) {                 // gate
    int n = i >> 6, k2 = i & 63;
    *(unsigned int*)&lwt[4608 + n * 136 + 2 * k2] = w32[2048 + i];
  }
  for (int i = t; i < 4096; i += 256) {                 // cand
    int n = i >> 6, k2 = i & 63;
    *(unsigned int*)&lwt[13312 + n * 136 + 2 * k2] = w32[6144 + i];
  }
  // stage state bf16 -> X cols 0-63
  for (int i = t; i < 4096; i += 256) {
    int row = i >> 6, col = i & 63;
    int ndg = min(nd0 + (row >> 1), kN - 1), b = row & 1;
    lx[row * 136 + col] = (unsigned short)f2b(ldf(state, b * kNH + ndg * 64 + col, f32));
  }
  // stage agg (packed both batches) -> X cols 64-127
  for (int i = t; i < 2048; i += 256) {
    int ndl = i >> 6, col = i & 63;
    unsigned int ag = agg[min(nd0 + ndl, kN - 1) * 64 + col];
    lx[(2 * ndl) * 136 + 64 + col]     = (unsigned short)(ag & 0xffffu);
    lx[(2 * ndl + 1) * 136 + 64 + col] = (unsigned short)(ag >> 16);
  }
  if (t < 64) sbias[t] = ldf(b_gate, t, f32);
  else if (t < 128) sbias[t] = ldf(b_cand, t - 64, f32);
  else sproj[t - 128] = projected[t - 128];
  if (t < 32) sfl[t] = (nd0 + t < kN) ? flags[nd0 + t] : 0;
  __syncthreads();

  int w = t >> 6, lane = t & 63;
  int q = lane >> 4, l15 = lane & 15;
  int rowb = w * 16;

  // --- msg phase: C[16x64] = agg[16x64] @ W_msg[64x64] ---
  short8_t a0 = *(const short8_t*)&lx[(rowb + l15) * 136 + 64 + q * 8];
  short8_t a1 = *(const short8_t*)&lx[(rowb + l15) * 136 + 96 + q * 8];
  f32x4_t msgc[4];
#pragma unroll
  for (int ct = 0; ct < 4; ++ct) {
    f32x4_t acc = {0.f, 0.f, 0.f, 0.f};
    short8_t b0 = *(const short8_t*)&lwt[(ct * 16 + l15) * 72 + q * 8];
    short8_t b1 = *(const short8_t*)&lwt[(ct * 16 + l15) * 72 + 32 + q * 8];
    acc = __builtin_amdgcn_mfma_f32_16x16x32_bf16(a0, b0, acc, 0, 0, 0);
    acc = __builtin_amdgcn_mfma_f32_16x16x32_bf16(a1, b1, acc, 0, 0, 0);
    msgc[ct] = acc;
  }
  // combined = msg + inject -> back into X cols 64-127 (own strip rows only)
#pragma unroll
  for (int ct = 0; ct < 4; ++ct) {
    int col = ct * 16 + l15;
    float pj0 = sproj[col], pj1 = sproj[64 + col];
#pragma unroll
    for (int r = 0; r < 4; ++r) {
      int row = rowb + q * 4 + r;
      int ndl = row >> 1, b = row & 1;
      float inj = sfl[ndl] ? (b ? pj1 : pj0) : 0.f;
      lx[row * 136 + 64 + col] = (unsigned short)f2b(msgc[ct][r] + inj);
    }
  }

  // --- gate/cand phase: K=128 over [state | combined] ---
  short8_t xa[4];
#pragma unroll
  for (int ks = 0; ks < 4; ++ks)
    xa[ks] = *(const short8_t*)&lx[(rowb + l15) * 136 + ks * 32 + q * 8];
#pragma unroll
  for (int ct = 0; ct < 4; ++ct) {
    f32x4_t accg = {0.f, 0.f, 0.f, 0.f}, accc = {0.f, 0.f, 0.f, 0.f};
#pragma unroll
    for (int ks = 0; ks < 4; ++ks) {
      short8_t bg = *(const short8_t*)&lwt[4608 + (ct * 16 + l15) * 136 + ks * 32 + q * 8];
      short8_t bc = *(const short8_t*)&lwt[13312 + (ct * 16 + l15) * 136 + ks * 32 + q * 8];
      accg = __builtin_amdgcn_mfma_f32_16x16x32_bf16(xa[ks], bg, accg, 0, 0, 0);
      accc = __builtin_amdgcn_mfma_f32_16x16x32_bf16(xa[ks], bc, accc, 0, 0, 0);
    }
    int col = ct * 16 + l15;
    float bgv = sbias[col], bcv = sbias[64 + col];
#pragma unroll
    for (int r = 0; r < 4; ++r) {
      int row = rowb + q * 4 + r;
      int nd = nd0 + (row >> 1), b = row & 1;
      if (nd >= kN) continue;
      float z  = 1.f / (1.f + __expf(-(accg[r] + bgv)));
      float cd = tanhf(accc[r] + bcv);
      float sv = ldf(state, b * kNH + nd * 64 + col, f32);
      float ns = (1.f - z) * sv + z * cd;
      stf(out, kOutOff + b * kNH + nd * 64 + col, ns, f32);
    }
  }
}

// --- readout: mean-pool efferent, tanh decode, policy heads -----------------
extern "C" __global__ void k_readout(const void* __restrict__ W_dec,
                                     const void* __restrict__ b_dec,
                                     const void* __restrict__ W_mean,
                                     const void* __restrict__ b_mean,
                                     const void* __restrict__ W_ls,
                                     const void* __restrict__ b_ls,
                                     const int* __restrict__ eff_idx,
                                     const int* __restrict__ dflag,
                                     void* __restrict__ out) {
  __shared__ float part[8][64];
  __shared__ float ro[128], dec[128];
  int f32 = dflag[0];
  int t = threadIdx.x;          // 512 threads = 8 waves
  int wv = t >> 6, lane = t & 63;
  int b = wv >> 2, g = wv & 3;  // wave -> (batch, quarter of eff list)
  float acc = 0.f;
#pragma unroll 4
  for (int i = 0; i < 64; ++i) {
    int n = eff_idx[g * 64 + i];
    acc += ldf(out, kOutOff + b * kNH + n * 64 + lane, f32);
  }
  part[wv][lane] = acc;
  __syncthreads();
  if (t < 128) {
    int bb = t >> 6, h = t & 63;
    float s = part[bb * 4 + 0][h] + part[bb * 4 + 1][h] +
              part[bb * 4 + 2][h] + part[bb * 4 + 3][h];
    ro[t] = s * (1.f / kEff);
  }
  __syncthreads();
  if (t < 128) {
    int bb = t >> 6, h = t & 63;
    float d = ldf(b_dec, h, f32);
    for (int k = 0; k < 64; ++k) d += ro[bb * 64 + k] * ldf(W_dec, k * 64 + h, f32);
    dec[t] = tanhf(d);
  }
  __syncthreads();
  if (t < kB * kA) {
    int bb = t / kA, a = t % kA;
    float m = ldf(b_mean, a, f32), l = ldf(b_ls, a, f32);
    for (int k = 0; k < 64; ++k) {
      float dv = dec[bb * 64 + k];
      m += dv * ldf(W_mean, k * kA + a, f32);
      l += dv * ldf(W_ls, k * kA + a, f32);
    }
    l = fminf(fmaxf(l, -5.f), 2.f);
    stf(out, t, m, f32);            // mean[2][18]
    stf(out, kB * kA + t, l, f32);  // log_std[2][18]
  }
}

extern "C" void kernel_launch(void* const* d_in, const int* in_sizes, int n_in,
                              void* d_out, int out_size, void* d_ws, size_t ws_size,
                              hipStream_t stream) {
  (void)in_sizes; (void)n_in; (void)out_size; (void)ws_size;
  const void* obs    = d_in[0];
  const void* state  = d_in[1];
  const void* W_in   = d_in[2];
  const void* b_in   = d_in[3];
  const void* W_msg  = d_in[4];
  const void* W_gate = d_in[5];
  const void* b_gate = d_in[6];
  const void* W_cand = d_in[7];
  const void* b_cand = d_in[8];
  const void* W_dec  = d_in[9];
  const void* b_dec  = d_in[10];
  const void* W_mean = d_in[11];
  const void* b_mean = d_in[12];
  const void* W_ls   = d_in[13];
  const void* b_ls   = d_in[14];
  const int* src = (const int*)d_in[15];
  const int* dst = (const int*)d_in[16];
  const int* aff = (const int*)d_in[17];
  const int* eff = (const int*)d_in[18];

  // workspace layout (~35 MB)
  int* wsp        = (int*)d_ws;
  int* flags      = wsp;                    // [N]     (memset 0)
  int* deg8       = flags + kN;             // [kN8]   (memset 0)
  int* row_off8   = deg8 + kN8;             // [kN8+1] -> pad kN8+64
  int* cursor8    = row_off8 + (kN8 + 64);  // [kN8]
  int* partials   = cursor8 + kN8;          // [512]
  int* dflag      = partials + 512;         // [16]
  float* projected = (float*)(dflag + 16);           // [128]
  int* sorted_src  = (int*)(projected + 128);        // [E]
  unsigned int* pk  = (unsigned int*)(sorted_src + kE);  // [N*H]
  unsigned int* agg = pk + kNH;                          // [N*H]
  unsigned short* wt = (unsigned short*)(agg + kNH);     // [20480] bf16

  hipMemsetAsync(flags, 0, size_t(kN + kN8) * sizeof(int), stream);  // flags+deg8
  k_front<<<1 + kHistBlocks, 256, 0, stream>>>(
      (const unsigned short*)W_cand, obs, W_in, b_in, aff, dst,
      dflag, flags, projected, deg8);
  k_pack<<<(kNH + 255) / 256, 256, 0, stream>>>(state, dflag, pk);
  k_wprep<<<80, 256, 0, stream>>>(W_msg, W_gate, W_cand, dflag, wt);
  k_scan1<<<kScanB8, 256, 0, stream>>>(deg8, row_off8, partials);
  k_scan2<<<1, 64, 0, stream>>>(partials, row_off8);
  k_scan3<<<(kN8 + 255) / 256, 256, 0, stream>>>(row_off8, partials, cursor8);
  k_scatter<<<kHistBlocks, 256, 0, stream>>>(src, dst, cursor8, sorted_src);
  k_gather<<<(kN + 3) / 4, 256, 0, stream>>>(pk, row_off8, sorted_src, agg);
  k_update<<<(kN + 31) / 32, 256, 0, stream>>>(state, wt, b_gate, b_cand,
                                               agg, flags, projected, dflag, d_out);
  k_readout<<<1, 512, 0, stream>>>(W_dec, b_dec, W_mean, b_mean, W_ls, b_ls, eff,
                                   dflag, d_out);
}

// Round 10
// 330.717 us; speedup vs baseline: 3.5805x; 1.1122x over previous
//
#include <hip/hip_runtime.h>
#include <hip/hip_bf16.h>

// Problem constants (WholeBrainRateModel)
constexpr int kN   = 50000;    // nodes
constexpr int kH   = 64;       // hidden
constexpr int kB   = 2;        // batch
constexpr int kE   = 1000000;  // edges
constexpr int kObs = 128;
constexpr int kA   = 18;
constexpr int kAff = 512;
constexpr int kEff = 256;
constexpr int kNH  = kN * kH;
constexpr int kOutOff = 2 * kB * kA;  // 72 elements: mean+log_std before next_state
constexpr int kHistBlocks = (kE + 1023) / 1024;   // 977
constexpr int kPackBlocks = kNH / 256;            // 12500
constexpr int kWprepBlocks = 80;
constexpr int kR   = 8;              // XCD-keyed regions
constexpr int kN8  = kR * kN;        // 400000 region-major CSR keys
constexpr int kScanB8 = (kN8 + 1023) / 1024;  // 391

typedef __attribute__((ext_vector_type(8))) short short8_t;  // 8 bf16 (4 VGPRs)
typedef __attribute__((ext_vector_type(4))) float f32x4_t;

// dtype-adaptive load/store (flag==1 -> float32 buffers, else bf16).
__device__ __forceinline__ float ldf(const void* p, int i, int f32) {
  if (f32) return ((const float*)p)[i];
  unsigned short u = ((const unsigned short*)p)[i];
  union { unsigned int x; float f; } v; v.x = ((unsigned int)u) << 16; return v.f;
}
__device__ __forceinline__ void stf(void* p, int i, float val, int f32) {
  if (f32) ((float*)p)[i] = val;
  else ((__hip_bfloat16*)p)[i] = __float2bfloat16(val);
}
__device__ __forceinline__ float lo16(unsigned int w) {
  union { unsigned int i; float f; } v; v.i = w << 16; return v.f;
}
__device__ __forceinline__ float hi16(unsigned int w) {
  union { unsigned int i; float f; } v; v.i = w & 0xffff0000u; return v.f;
}
__device__ __forceinline__ unsigned int f2b(float f) {  // rne bf16 bits
  union { float f; unsigned int u; } v; v.f = f;
  unsigned int r = v.u + 0x7fffu + ((v.u >> 16) & 1u);
  return r >> 16;
}
// wave-0 dtype detector (identical data in every block -> identical answer)
__device__ __forceinline__ int detect64(const unsigned short* wprobe, int t) {
  int hits = 0;
  for (int k = 0; k < 4; ++k) {
    unsigned short u = wprobe[(t * 4 + k) * 2];
    int e = (u >> 7) & 0xFF;
    if ((u & 0x7FFFu) != 0 && e >= 108 && e <= 128) hits++;
  }
  for (int off = 32; off; off >>= 1) hits += __shfl_down(hits, off);
  return (hits < 128) ? 1 : 0;  // few plausible-bf16 => f32
}

// --- fused prep: b0 = detect+flags+proj; then hist | pack | wprep -----------
extern "C" __global__ void k_prep(const unsigned short* __restrict__ wprobe,
                                  const void* __restrict__ obs,
                                  const void* __restrict__ W_in,
                                  const void* __restrict__ b_in,
                                  const int* __restrict__ aff_idx,
                                  const int* __restrict__ dst,
                                  const void* __restrict__ state,
                                  const void* __restrict__ W_msg,
                                  const void* __restrict__ W_gate,
                                  const void* __restrict__ W_cand,
                                  int* __restrict__ dflag,
                                  int* __restrict__ flags,
                                  float* __restrict__ projected,
                                  int* __restrict__ deg8,
                                  unsigned int* __restrict__ pack,
                                  unsigned short* __restrict__ wt) {
  int t = threadIdx.x, b = blockIdx.x;
  if (b == 0) {
    __shared__ int sflag;
    if (t < 64) { int f = detect64(wprobe, t); if (t == 0) { sflag = f; dflag[0] = f; } }
    __syncthreads();
    int f32 = sflag;
    for (int j = t; j < kAff; j += 256) flags[aff_idx[j]] = 1;
    if (t < kB * kH) {
      int bb = t >> 6, h = t & 63;
      float acc = ldf(b_in, h, f32);
      for (int o = 0; o < kObs; ++o)
        acc += ldf(obs, bb * kObs + o, f32) * ldf(W_in, o * kH + h, f32);
      projected[t] = acc;
    }
  } else if (b <= kHistBlocks) {
    // region-keyed histogram: rep = edge-block & 7 (same mapping as k_scatter)
    int j = b - 1, rep = j & 7;
    int base = j * 1024 + t;
#pragma unroll
    for (int k = 0; k < 4; ++k) {
      int e = base + k * 256;
      if (e < kE) atomicAdd(&deg8[rep * kN + dst[e]], 1);
    }
  } else if (b < 1 + kHistBlocks + kPackBlocks) {
    __shared__ int sflag;
    if (t < 64) { int f = detect64(wprobe, t); if (t == 0) sflag = f; }
    __syncthreads();
    int f32 = sflag;
    int i = (b - 1 - kHistBlocks) * 256 + t;
    if (i < kNH) {
      float v0 = ldf(state, i, f32);
      float v1 = ldf(state, kNH + i, f32);
      pack[i] = f2b(v0) | (f2b(v1) << 16);
    }
  } else {
    __shared__ int sflag;
    if (t < 64) { int f = detect64(wprobe, t); if (t == 0) sflag = f; }
    __syncthreads();
    int f32 = sflag;
    int i = (b - 1 - kHistBlocks - kPackBlocks) * 256 + t;  // 0..20479
    if (i < 4096) {
      int n = i >> 6, k = i & 63;
      wt[i] = (unsigned short)f2b(ldf(W_msg, k * 64 + n, f32));
    } else if (i < 12288) {
      int j = i - 4096; int n = j >> 7, k = j & 127;
      wt[i] = (unsigned short)f2b(ldf(W_gate, k * 64 + n, f32));
    } else if (i < 20480) {
      int j = i - 12288; int n = j >> 7, k = j & 127;
      wt[i] = (unsigned short)f2b(ldf(W_cand, k * 64 + n, f32));
    }
  }
}

// --- scan over kN8 region-major keys ----------------------------------------
extern "C" __global__ void k_scan1(const int* __restrict__ deg8,
                                   int* __restrict__ row_off8,
                                   int* __restrict__ partials) {
  __shared__ int sd[256];
  int t = threadIdx.x;
  int base = blockIdx.x * 1024 + t * 4;
  int d0 = (base + 0 < kN8) ? deg8[base + 0] : 0;
  int d1 = (base + 1 < kN8) ? deg8[base + 1] : 0;
  int d2 = (base + 2 < kN8) ? deg8[base + 2] : 0;
  int d3 = (base + 3 < kN8) ? deg8[base + 3] : 0;
  int s4 = d0 + d1 + d2 + d3;
  sd[t] = s4;
  __syncthreads();
  for (int off = 1; off < 256; off <<= 1) {
    int v = (t >= off) ? sd[t - off] : 0;
    __syncthreads();
    sd[t] += v;
    __syncthreads();
  }
  int excl = sd[t] - s4;
  if (t == 255) partials[blockIdx.x] = sd[255];
  if (base + 0 < kN8) row_off8[base + 0] = excl;
  excl += d0;
  if (base + 1 < kN8) row_off8[base + 1] = excl;
  excl += d1;
  if (base + 2 < kN8) row_off8[base + 2] = excl;
  excl += d2;
  if (base + 3 < kN8) row_off8[base + 3] = excl;
}

// scan2 folded in: each block parallel-sums partials[0..chunk) itself.
extern "C" __global__ void k_scan3(int* __restrict__ row_off8,
                                   const int* __restrict__ partials,
                                   int* __restrict__ cursor8) {
  __shared__ int sd[256];
  int t = threadIdx.x;
  int chunk = blockIdx.x >> 2;           // 256 keys/block, 1024 keys/chunk
  int s = 0;
  for (int j = t; j < chunk; j += 256) s += partials[j];
  sd[t] = s;
  __syncthreads();
  for (int off = 128; off; off >>= 1) {
    if (t < off) sd[t] += sd[t + off];
    __syncthreads();
  }
  int base = sd[0];
  int i = blockIdx.x * 256 + t;
  if (i < kN8) {
    int v = row_off8[i] + base;
    row_off8[i] = v;
    cursor8[i] = v;
  }
  if (blockIdx.x == 0 && t == 0) row_off8[kN8] = kE;
}

// --- scatter: edge -> region-major CSR slot (region = XCD under heuristic) --
extern "C" __global__ void k_scatter(const int* __restrict__ src,
                                     const int* __restrict__ dst,
                                     int* __restrict__ cursor8,
                                     int* __restrict__ sorted_src) {
  int rep = blockIdx.x & 7;    // == (e>>10)&7 for all this block's edges
  int base = blockIdx.x * 1024 + threadIdx.x;
#pragma unroll
  for (int k = 0; k < 4; ++k) {
    int e = base + k * 256;
    if (e < kE) {
      int pos = atomicAdd(&cursor8[rep * kN + dst[e]], 1);
      sorted_src[pos] = src[e];
    }
  }
}

// --- gather: one wave per node, sum over its 8 region spans -----------------
extern "C" __global__ __launch_bounds__(256) void k_gather(
    const unsigned int* __restrict__ pack,
    const int* __restrict__ row_off8,
    const int* __restrict__ sorted_src,
    unsigned int* __restrict__ agg) {
  int wave = threadIdx.x >> 6, lane = threadIdx.x & 63;
  int n = blockIdx.x * 4 + wave;
  if (n >= kN) return;
  // 16 span boundaries in one parallel load: lane l<16 -> region l&7, +(l>>3)
  int bv = 0;
  if (lane < 16) bv = row_off8[(lane & 7) * kN + n + (lane >> 3)];
  float a0 = 0.f, a1 = 0.f;
#pragma unroll 1
  for (int r = 0; r < 8; ++r) {
    int s = __shfl(bv, r), en = __shfl(bv, r + 8);
    for (int e = s; e < en; e += 4) {
      int m = en - e;
      int i0 = sorted_src[e];
      int i1 = sorted_src[m > 1 ? e + 1 : e];
      int i2 = sorted_src[m > 2 ? e + 2 : e];
      int i3 = sorted_src[m > 3 ? e + 3 : e];
      unsigned int w0 = pack[i0 * 64 + lane];
      unsigned int w1 = pack[i1 * 64 + lane];
      unsigned int w2 = pack[i2 * 64 + lane];
      unsigned int w3 = pack[i3 * 64 + lane];
      a0 += lo16(w0); a1 += hi16(w0);
      if (m > 1) { a0 += lo16(w1); a1 += hi16(w1); }
      if (m > 2) { a0 += lo16(w2); a1 += hi16(w2); }
      if (m > 3) { a0 += lo16(w3); a1 += hi16(w3); }
    }
  }
  agg[n * 64 + lane] = f2b(a0) | (f2b(a1) << 16);
}

// --- update (MFMA): msg = agg@W_msg (+inject), GRU gate/cand, next_state ----
// Block: 32 nodes x 2 batches = 64 M-rows. Wave w owns rows [16w,16w+16).
// X LDS [64][136]: cols 0-63 state bf16, cols 64-127 agg -> combined.
// Staging fully vectorized from pk/agg (already bf16-packed, both batches).
// A-frag: lane holds A[m=lane&15][k=(lane>>4)*8+j]; B-frag: B[k][n=lane&15];
// C: col=lane&15, row=(lane>>4)*4+reg (verified mappings, learn_hip m89/m91).
extern "C" __global__ __launch_bounds__(256) void k_update(
    const unsigned int* __restrict__ pk,
    const unsigned short* __restrict__ wt,   // prepped bf16 Wt msg|gate|cand
    const void* __restrict__ b_gate,
    const void* __restrict__ b_cand,
    const unsigned int* __restrict__ agg,
    const int* __restrict__ flags,
    const float* __restrict__ projected,
    const int* __restrict__ dflag,
    void* __restrict__ out) {
  __shared__ uint4 lw4[2752];    // 44032 B: msg@0(72 u16/row) gate@4608 cand@13312(136/row)
  __shared__ uint4 lx4[1088];    // 17408 B
  __shared__ float sbias[128];   // gate 0-63 | cand 64-127
  __shared__ float sproj[128];
  __shared__ int   sfl[32];
  unsigned short* lwt = (unsigned short*)lw4;
  unsigned short* lx  = (unsigned short*)lx4;
  int f32 = dflag[0];
  int t = threadIdx.x;
  int nd0 = blockIdx.x * 32;

  // weights: uint4 copies (msg 512, gate 1024, cand 1024 chunks)
  const uint4* w4 = (const uint4*)wt;
  for (int i = t; i < 512; i += 256)  { int n = i >> 3, c = i & 7;  lw4[n * 9 + c] = w4[n * 8 + c]; }
  for (int i = t; i < 1024; i += 256) { int n = i >> 4, c = i & 15; lw4[576 + n * 17 + c] = w4[512 + n * 16 + c]; }
  for (int i = t; i < 1024; i += 256) { int n = i >> 4, c = i & 15; lw4[1664 + n * 17 + c] = w4[1536 + n * 16 + c]; }

  // X: uint4 loads from pk/agg, uint2 LDS writes (split batches to rows)
  const uint4* pk4 = (const uint4*)pk;
  const uint4* ag4 = (const uint4*)agg;
  for (int i = t; i < 512; i += 256) {
    int ndl = i >> 4, c4 = i & 15;
    int ndg = min(nd0 + ndl, kN - 1);
    uint4 pv = pk4[ndg * 16 + c4];
    uint4 av = ag4[ndg * 16 + c4];
    *(uint2*)&lx[(2 * ndl) * 136 + c4 * 4] =
        make_uint2((pv.x & 0xffffu) | (pv.y << 16), (pv.z & 0xffffu) | (pv.w << 16));
    *(uint2*)&lx[(2 * ndl + 1) * 136 + c4 * 4] =
        make_uint2((pv.x >> 16) | (pv.y & 0xffff0000u), (pv.z >> 16) | (pv.w & 0xffff0000u));
    *(uint2*)&lx[(2 * ndl) * 136 + 64 + c4 * 4] =
        make_uint2((av.x & 0xffffu) | (av.y << 16), (av.z & 0xffffu) | (av.w << 16));
    *(uint2*)&lx[(2 * ndl + 1) * 136 + 64 + c4 * 4] =
        make_uint2((av.x >> 16) | (av.y & 0xffff0000u), (av.z >> 16) | (av.w & 0xffff0000u));
  }
  if (t < 64) sbias[t] = ldf(b_gate, t, f32);
  else if (t < 128) sbias[t] = ldf(b_cand, t - 64, f32);
  else sproj[t - 128] = projected[t - 128];
  if (t < 32) sfl[t] = (nd0 + t < kN) ? flags[nd0 + t] : 0;
  __syncthreads();

  int w = t >> 6, lane = t & 63;
  int q = lane >> 4, l15 = lane & 15;
  int rowb = w * 16;

  // --- msg phase: C[16x64] = agg[16x64] @ W_msg[64x64] ---
  short8_t a0 = *(const short8_t*)&lx[(rowb + l15) * 136 + 64 + q * 8];
  short8_t a1 = *(const short8_t*)&lx[(rowb + l15) * 136 + 96 + q * 8];
  f32x4_t msgc[4];
#pragma unroll
  for (int ct = 0; ct < 4; ++ct) {
    f32x4_t acc = {0.f, 0.f, 0.f, 0.f};
    short8_t b0 = *(const short8_t*)&lwt[(ct * 16 + l15) * 72 + q * 8];
    short8_t b1 = *(const short8_t*)&lwt[(ct * 16 + l15) * 72 + 32 + q * 8];
    acc = __builtin_amdgcn_mfma_f32_16x16x32_bf16(a0, b0, acc, 0, 0, 0);
    acc = __builtin_amdgcn_mfma_f32_16x16x32_bf16(a1, b1, acc, 0, 0, 0);
    msgc[ct] = acc;
  }
  // combined = msg + inject -> back into X cols 64-127 (own strip rows only)
#pragma unroll
  for (int ct = 0; ct < 4; ++ct) {
    int col = ct * 16 + l15;
    float pj0 = sproj[col], pj1 = sproj[64 + col];
#pragma unroll
    for (int r = 0; r < 4; ++r) {
      int row = rowb + q * 4 + r;
      int ndl = row >> 1, b = row & 1;
      float inj = sfl[ndl] ? (b ? pj1 : pj0) : 0.f;
      lx[row * 136 + 64 + col] = (unsigned short)f2b(msgc[ct][r] + inj);
    }
  }

  // --- gate/cand phase: K=128 over [state | combined] ---
  short8_t xa[4];
#pragma unroll
  for (int ks = 0; ks < 4; ++ks)
    xa[ks] = *(const short8_t*)&lx[(rowb + l15) * 136 + ks * 32 + q * 8];
#pragma unroll
  for (int ct = 0; ct < 4; ++ct) {
    f32x4_t accg = {0.f, 0.f, 0.f, 0.f}, accc = {0.f, 0.f, 0.f, 0.f};
#pragma unroll
    for (int ks = 0; ks < 4; ++ks) {
      short8_t bg = *(const short8_t*)&lwt[4608 + (ct * 16 + l15) * 136 + ks * 32 + q * 8];
      short8_t bc = *(const short8_t*)&lwt[13312 + (ct * 16 + l15) * 136 + ks * 32 + q * 8];
      accg = __builtin_amdgcn_mfma_f32_16x16x32_bf16(xa[ks], bg, accg, 0, 0, 0);
      accc = __builtin_amdgcn_mfma_f32_16x16x32_bf16(xa[ks], bc, accc, 0, 0, 0);
    }
    int col = ct * 16 + l15;
    float bgv = sbias[col], bcv = sbias[64 + col];
#pragma unroll
    for (int rp = 0; rp < 2; ++rp) {
      int rowe = rowb + q * 4 + 2 * rp;      // even row; odd row = same node, batch1
      int nd = nd0 + (rowe >> 1);
      if (nd >= kN) continue;
      unsigned int pv = pk[nd * 64 + col];   // both batches' state, bf16
      float z0 = 1.f / (1.f + __expf(-(accg[2 * rp] + bgv)));
      float c0 = tanhf(accc[2 * rp] + bcv);
      stf(out, kOutOff + nd * 64 + col, (1.f - z0) * lo16(pv) + z0 * c0, f32);
      float z1 = 1.f / (1.f + __expf(-(accg[2 * rp + 1] + bgv)));
      float c1 = tanhf(accc[2 * rp + 1] + bcv);
      stf(out, kOutOff + kNH + nd * 64 + col, (1.f - z1) * hi16(pv) + z1 * c1, f32);
    }
  }
}

// --- readout: mean-pool efferent, tanh decode, policy heads -----------------
extern "C" __global__ void k_readout(const void* __restrict__ W_dec,
                                     const void* __restrict__ b_dec,
                                     const void* __restrict__ W_mean,
                                     const void* __restrict__ b_mean,
                                     const void* __restrict__ W_ls,
                                     const void* __restrict__ b_ls,
                                     const int* __restrict__ eff_idx,
                                     const int* __restrict__ dflag,
                                     void* __restrict__ out) {
  __shared__ float part[8][64];
  __shared__ float ro[128], dec[128];
  int f32 = dflag[0];
  int t = threadIdx.x;          // 512 threads = 8 waves
  int wv = t >> 6, lane = t & 63;
  int b = wv >> 2, g = wv & 3;  // wave -> (batch, quarter of eff list)
  float acc = 0.f;
#pragma unroll 4
  for (int i = 0; i < 64; ++i) {
    int n = eff_idx[g * 64 + i];
    acc += ldf(out, kOutOff + b * kNH + n * 64 + lane, f32);
  }
  part[wv][lane] = acc;
  __syncthreads();
  if (t < 128) {
    int bb = t >> 6, h = t & 63;
    float s = part[bb * 4 + 0][h] + part[bb * 4 + 1][h] +
              part[bb * 4 + 2][h] + part[bb * 4 + 3][h];
    ro[t] = s * (1.f / kEff);
  }
  __syncthreads();
  if (t < 128) {
    int bb = t >> 6, h = t & 63;
    float d = ldf(b_dec, h, f32);
    for (int k = 0; k < 64; ++k) d += ro[bb * 64 + k] * ldf(W_dec, k * 64 + h, f32);
    dec[t] = tanhf(d);
  }
  __syncthreads();
  if (t < kB * kA) {
    int bb = t / kA, a = t % kA;
    float m = ldf(b_mean, a, f32), l = ldf(b_ls, a, f32);
    for (int k = 0; k < 64; ++k) {
      float dv = dec[bb * 64 + k];
      m += dv * ldf(W_mean, k * kA + a, f32);
      l += dv * ldf(W_ls, k * kA + a, f32);
    }
    l = fminf(fmaxf(l, -5.f), 2.f);
    stf(out, t, m, f32);            // mean[2][18]
    stf(out, kB * kA + t, l, f32);  // log_std[2][18]
  }
}

extern "C" void kernel_launch(void* const* d_in, const int* in_sizes, int n_in,
                              void* d_out, int out_size, void* d_ws, size_t ws_size,
                              hipStream_t stream) {
  (void)in_sizes; (void)n_in; (void)out_size; (void)ws_size;
  const void* obs    = d_in[0];
  const void* state  = d_in[1];
  const void* W_in   = d_in[2];
  const void* b_in   = d_in[3];
  const void* W_msg  = d_in[4];
  const void* W_gate = d_in[5];
  const void* b_gate = d_in[6];
  const void* W_cand = d_in[7];
  const void* b_cand = d_in[8];
  const void* W_dec  = d_in[9];
  const void* b_dec  = d_in[10];
  const void* W_mean = d_in[11];
  const void* b_mean = d_in[12];
  const void* W_ls   = d_in[13];
  const void* b_ls   = d_in[14];
  const int* src = (const int*)d_in[15];
  const int* dst = (const int*)d_in[16];
  const int* aff = (const int*)d_in[17];
  const int* eff = (const int*)d_in[18];

  // workspace layout (~35 MB)
  int* wsp        = (int*)d_ws;
  int* flags      = wsp;                    // [N]     (memset 0)
  int* deg8       = flags + kN;             // [kN8]   (memset 0)
  int* row_off8   = deg8 + kN8;             // [kN8+1] -> pad kN8+64
  int* cursor8    = row_off8 + (kN8 + 64);  // [kN8]
  int* partials   = cursor8 + kN8;          // [512]
  int* dflag      = partials + 512;         // [16]
  float* projected = (float*)(dflag + 16);           // [128]
  int* sorted_src  = (int*)(projected + 128);        // [E]
  unsigned int* pk  = (unsigned int*)(sorted_src + kE);  // [N*H]
  unsigned int* agg = pk + kNH;                          // [N*H]
  unsigned short* wt = (unsigned short*)(agg + kNH);     // [20480] bf16

  hipMemsetAsync(flags, 0, size_t(kN + kN8) * sizeof(int), stream);  // flags+deg8
  k_prep<<<1 + kHistBlocks + kPackBlocks + kWprepBlocks, 256, 0, stream>>>(
      (const unsigned short*)W_cand, obs, W_in, b_in, aff, dst, state,
      W_msg, W_gate, W_cand, dflag, flags, projected, deg8, pk, wt);
  k_scan1<<<kScanB8, 256, 0, stream>>>(deg8, row_off8, partials);
  k_scan3<<<(kN8 + 255) / 256, 256, 0, stream>>>(row_off8, partials, cursor8);
  k_scatter<<<kHistBlocks, 256, 0, stream>>>(src, dst, cursor8, sorted_src);
  k_gather<<<(kN + 3) / 4, 256, 0, stream>>>(pk, row_off8, sorted_src, agg);
  k_update<<<(kN + 31) / 32, 256, 0, stream>>>(pk, wt, b_gate, b_cand,
                                               agg, flags, projected, dflag, d_out);
  k_readout<<<1, 512, 0, stream>>>(W_dec, b_dec, W_mean, b_mean, W_ls, b_ls, eff,
                                   dflag, d_out);
}